// Round 1
// baseline (2140.472 us; speedup 1.0000x reference)
//
#include <hip/hip_runtime.h>

constexpr int NC = 100000;
constexpr int NQ = 20000;
constexpr int FC = 300;
constexpr int FQ = 768;
constexpr int HIDDEN = 128;
constexpr int NEDGE = 400000;
constexpr float SCALE = 0.17677669529663687f;  // 1/sqrt(32)

__device__ __forceinline__ float gelu_f(float x) {
  return 0.5f * x * (1.0f + erff(x * 0.7071067811865476f));
}

// ---------------- CSR build ----------------
__global__ void k_count(const int* __restrict__ dst, int* __restrict__ counts, int n) {
  int i = blockIdx.x * 256 + threadIdx.x;
  if (i < n) atomicAdd(&counts[dst[i]], 1);
}

__global__ void k_scan_block(const int* __restrict__ in, int* __restrict__ out,
                             int* __restrict__ bsum, int n) {
  __shared__ int s[256];
  int tid = threadIdx.x;
  int i = blockIdx.x * 256 + tid;
  int v = (i < n) ? in[i] : 0;
  s[tid] = v;
  __syncthreads();
  for (int off = 1; off < 256; off <<= 1) {
    int t = (tid >= off) ? s[tid - off] : 0;
    __syncthreads();
    s[tid] += t;
    __syncthreads();
  }
  if (i < n) out[i] = s[tid] - v;        // exclusive within block
  if (tid == 255) bsum[blockIdx.x] = s[255];
}

__global__ void k_scan_sums(int* __restrict__ bsum, int nb) {
  __shared__ int s[1024];
  int tid = threadIdx.x;
  int v = (tid < nb) ? bsum[tid] : 0;
  s[tid] = v;
  __syncthreads();
  for (int off = 1; off < 1024; off <<= 1) {
    int t = (tid >= off) ? s[tid - off] : 0;
    __syncthreads();
    s[tid] += t;
    __syncthreads();
  }
  if (tid < nb) bsum[tid] = s[tid] - v;  // exclusive block offsets
}

__global__ void k_scan_add(int* __restrict__ ptr, const int* __restrict__ bsum, int n, int total) {
  int i = blockIdx.x * 256 + threadIdx.x;
  if (i < n) ptr[i] += bsum[blockIdx.x];
  if (i == 0) ptr[n] = total;
}

__global__ void k_copy(int* __restrict__ dst, const int* __restrict__ src, int n) {
  int i = blockIdx.x * 256 + threadIdx.x;
  if (i < n) dst[i] = src[i];
}

__global__ void k_scatter(const int* __restrict__ src, const int* __restrict__ dst,
                          int* __restrict__ cursor, int* __restrict__ srcs_out, int n) {
  int i = blockIdx.x * 256 + threadIdx.x;
  if (i < n) {
    int p = atomicAdd(&cursor[dst[i]], 1);
    srcs_out[p] = src[i];
  }
}

// ---------------- weight fold:  Wout[i][h*32+f] = mul[h] * sum_d Win[i][h*32+d]*rel[h][d][f]
__global__ void fold_kernel(const float* __restrict__ Win, const float* __restrict__ bin,
                            const float* __restrict__ rel, const float* __restrict__ prel,
                            float scale, float* __restrict__ Wout, float* __restrict__ bout) {
  int i = blockIdx.x;          // input row 0..127
  int col = threadIdx.x;       // 0..127
  int h = col >> 5, f = col & 31;
  float m = (prel ? prel[h] : 1.0f) * scale;
  float s = 0.0f;
  #pragma unroll
  for (int d = 0; d < 32; ++d)
    s += Win[i * 128 + h * 32 + d] * rel[(h * 32 + d) * 32 + f];
  Wout[i * 128 + col] = s * m;
  if (i == 0) {
    float sb = 0.0f;
    #pragma unroll
    for (int d = 0; d < 32; ++d)
      sb += bin[h * 32 + d] * rel[(h * 32 + d) * 32 + f];
    bout[col] = sb * m;
  }
}

// ---------------- generic GEMM: C[M x 128] = epi(A[M x K] @ B[K x 128] + bias)
// MODE 0: plain   MODE 1: relu   MODE 2: skip-gate (x = g*(v+b)+(1-g)*xold)
// GIN 1: apply exact gelu to A elements on load.
template <int MODE, int GIN>
__global__ __launch_bounds__(256) void gemm128(
    const float* __restrict__ A, const float* __restrict__ B,
    const float* __restrict__ bias, float* __restrict__ C,
    const float* __restrict__ Xold, const float* __restrict__ skip_p,
    int M, int K) {
  __shared__ float As[64][65];
  __shared__ float Bs[64][128];
  const int tid = threadIdx.x;
  const int m0 = blockIdx.x * 64;
  const int tx = tid & 15, ty = tid >> 4;

  float acc[4][8];
  #pragma unroll
  for (int i = 0; i < 4; ++i)
    #pragma unroll
    for (int j = 0; j < 8; ++j) acc[i][j] = 0.0f;

  for (int k0 = 0; k0 < K; k0 += 64) {
    // A tile: 64 rows x 64 cols
    #pragma unroll
    for (int i = 0; i < 4; ++i) {
      int r = (tid >> 4) + 16 * i;
      int c = (tid & 15) * 4;
      int gr = m0 + r;
      float4 v = make_float4(0.f, 0.f, 0.f, 0.f);
      if (gr < M) {
        int gc = k0 + c;
        if (gc + 3 < K) {
          v = *(const float4*)&A[(size_t)gr * K + gc];
        } else {
          if (gc + 0 < K) v.x = A[(size_t)gr * K + gc + 0];
          if (gc + 1 < K) v.y = A[(size_t)gr * K + gc + 1];
          if (gc + 2 < K) v.z = A[(size_t)gr * K + gc + 2];
          if (gc + 3 < K) v.w = A[(size_t)gr * K + gc + 3];
        }
      }
      if (GIN) { v.x = gelu_f(v.x); v.y = gelu_f(v.y); v.z = gelu_f(v.z); v.w = gelu_f(v.w); }
      As[r][c + 0] = v.x; As[r][c + 1] = v.y; As[r][c + 2] = v.z; As[r][c + 3] = v.w;
    }
    // B tile: 64 rows(k) x 128 cols
    #pragma unroll
    for (int i = 0; i < 8; ++i) {
      int r = (tid >> 5) + 8 * i;
      int c = (tid & 31) * 4;
      float4 v = make_float4(0.f, 0.f, 0.f, 0.f);
      int gr = k0 + r;
      if (gr < K) v = *(const float4*)&B[(size_t)gr * 128 + c];
      *(float4*)&Bs[r][c] = v;
    }
    __syncthreads();

    int kmax = (K - k0 >= 64) ? 64 : (K - k0);
    if (kmax == 64) {
      #pragma unroll 8
      for (int kk = 0; kk < 64; ++kk) {
        float a[4];
        #pragma unroll
        for (int i = 0; i < 4; ++i) a[i] = As[ty * 4 + i][kk];
        float4 bl = *(const float4*)&Bs[kk][tx * 4];
        float4 bh = *(const float4*)&Bs[kk][64 + tx * 4];
        float b[8] = {bl.x, bl.y, bl.z, bl.w, bh.x, bh.y, bh.z, bh.w};
        #pragma unroll
        for (int i = 0; i < 4; ++i)
          #pragma unroll
          for (int j = 0; j < 8; ++j) acc[i][j] = fmaf(a[i], b[j], acc[i][j]);
      }
    } else {
      for (int kk = 0; kk < kmax; ++kk) {
        float a[4];
        #pragma unroll
        for (int i = 0; i < 4; ++i) a[i] = As[ty * 4 + i][kk];
        float4 bl = *(const float4*)&Bs[kk][tx * 4];
        float4 bh = *(const float4*)&Bs[kk][64 + tx * 4];
        float b[8] = {bl.x, bl.y, bl.z, bl.w, bh.x, bh.y, bh.z, bh.w};
        #pragma unroll
        for (int i = 0; i < 4; ++i)
          #pragma unroll
          for (int j = 0; j < 8; ++j) acc[i][j] = fmaf(a[i], b[j], acc[i][j]);
      }
    }
    __syncthreads();
  }

  float g = 1.0f;
  if (MODE == 2) g = 1.0f / (1.0f + __expf(-skip_p[0]));

  #pragma unroll
  for (int i = 0; i < 4; ++i) {
    int row = m0 + ty * 4 + i;
    if (row >= M) continue;
    // low cols: tx*4 .. tx*4+3
    {
      int c0 = tx * 4;
      float4 o;
      o.x = acc[i][0] + bias[c0 + 0];
      o.y = acc[i][1] + bias[c0 + 1];
      o.z = acc[i][2] + bias[c0 + 2];
      o.w = acc[i][3] + bias[c0 + 3];
      if (MODE == 1) { o.x = fmaxf(o.x, 0.f); o.y = fmaxf(o.y, 0.f); o.z = fmaxf(o.z, 0.f); o.w = fmaxf(o.w, 0.f); }
      if (MODE == 2) {
        const float* xo = &Xold[(size_t)row * 128 + c0];
        o.x = g * o.x + (1.f - g) * xo[0];
        o.y = g * o.y + (1.f - g) * xo[1];
        o.z = g * o.z + (1.f - g) * xo[2];
        o.w = g * o.w + (1.f - g) * xo[3];
      }
      *(float4*)&C[(size_t)row * 128 + c0] = o;
    }
    // high cols: 64 + tx*4 ..
    {
      int c0 = 64 + tx * 4;
      float4 o;
      o.x = acc[i][4] + bias[c0 + 0];
      o.y = acc[i][5] + bias[c0 + 1];
      o.z = acc[i][6] + bias[c0 + 2];
      o.w = acc[i][7] + bias[c0 + 3];
      if (MODE == 1) { o.x = fmaxf(o.x, 0.f); o.y = fmaxf(o.y, 0.f); o.z = fmaxf(o.z, 0.f); o.w = fmaxf(o.w, 0.f); }
      if (MODE == 2) {
        const float* xo = &Xold[(size_t)row * 128 + c0];
        o.x = g * o.x + (1.f - g) * xo[0];
        o.y = g * o.y + (1.f - g) * xo[1];
        o.z = g * o.z + (1.f - g) * xo[2];
        o.w = g * o.w + (1.f - g) * xo[3];
      }
      *(float4*)&C[(size_t)row * 128 + c0] = o;
    }
  }
}

// ---------------- attention aggregation: one wave per dst node, one edge type
__global__ __launch_bounds__(256) void attn_kernel(
    const float* __restrict__ q,     // [Ndst x 128]
    const float* __restrict__ krel,  // [Nsrc x 128] (p_rel*scale folded in)
    const float* __restrict__ vrel,  // [Nsrc x 128]
    const int* __restrict__ ptr,     // [Ndst+1]
    const int* __restrict__ srcs,    // [NEDGE]
    float* __restrict__ agg,         // [Ndst x 128] (+=)
    float* __restrict__ logits_ws,   // [NEDGE*4]
    int Ndst) {
  int wave = threadIdx.x >> 6;
  int lane = threadIdx.x & 63;
  int n = blockIdx.x * 4 + wave;
  bool active = (n < Ndst);
  int start = 0, end = 0;
  float2 q2 = make_float2(0.f, 0.f);
  if (active) {
    start = ptr[n];
    end = ptr[n + 1];
    q2 = *(const float2*)&q[(size_t)n * 128 + lane * 2];
  }
  int g = lane & 15;
  int h = lane >> 4;

  float mx = -3.0e38f;
  for (int e = start; e < end; ++e) {
    int s = srcs[e];
    float2 kr = *(const float2*)&krel[(size_t)s * 128 + lane * 2];
    float p = q2.x * kr.x + q2.y * kr.y;
    p += __shfl_xor(p, 1);
    p += __shfl_xor(p, 2);
    p += __shfl_xor(p, 4);
    p += __shfl_xor(p, 8);
    if (g == 0) logits_ws[(size_t)e * 4 + h] = p;
    mx = fmaxf(mx, p);
  }
  __syncthreads();  // make lead-lane logit stores visible to their 16-lane groups

  float sum = 0.f;
  float2 acc = make_float2(0.f, 0.f);
  for (int e = start; e < end; ++e) {
    int s = srcs[e];
    float lg = logits_ws[(size_t)e * 4 + h];
    float ex = __expf(lg - mx);
    sum += ex;
    float2 vr = *(const float2*)&vrel[(size_t)s * 128 + lane * 2];
    acc.x += ex * vr.x;
    acc.y += ex * vr.y;
  }
  if (active && start < end) {
    float inv = 1.0f / (sum + 1e-16f);
    float2 a2 = *(float2*)&agg[(size_t)n * 128 + lane * 2];
    a2.x += acc.x * inv;
    a2.y += acc.y * inv;
    *(float2*)&agg[(size_t)n * 128 + lane * 2] = a2;
  }
}

// ---------------- final projection: out[M x 8] = A[M x 128] @ W[128 x 8] + b
__global__ __launch_bounds__(256) void gemm_out(const float* __restrict__ A,
                                                const float* __restrict__ W,
                                                const float* __restrict__ b,
                                                float* __restrict__ out, int M) {
  __shared__ float Ws[1024];
  __shared__ float As[32][129];
  int tid = threadIdx.x;
  int m0 = blockIdx.x * 32;
  *(float4*)&Ws[tid * 4] = *(const float4*)&W[tid * 4];
  #pragma unroll
  for (int i = 0; i < 4; ++i) {
    int r = (tid >> 5) + 8 * i;
    int c = (tid & 31) * 4;
    float4 v = make_float4(0.f, 0.f, 0.f, 0.f);
    if (m0 + r < M) v = *(const float4*)&A[(size_t)(m0 + r) * 128 + c];
    As[r][c + 0] = v.x; As[r][c + 1] = v.y; As[r][c + 2] = v.z; As[r][c + 3] = v.w;
  }
  __syncthreads();
  int r = tid >> 3, c = tid & 7;
  float sum = b[c];
  #pragma unroll 16
  for (int k = 0; k < 128; ++k) sum = fmaf(As[r][k], Ws[k * 8 + c], sum);
  if (m0 + r < M) out[(size_t)(m0 + r) * 8 + c] = sum;
}

// ---------------- host orchestration ----------------
static inline size_t align256(size_t x) { return (x + 255) & ~(size_t)255; }

extern "C" void kernel_launch(void* const* d_in, const int* in_sizes, int n_in,
                              void* d_out, int out_size, void* d_ws, size_t ws_size,
                              hipStream_t stream) {
  const float* x_context = (const float*)d_in[0];
  const float* x_question = (const float*)d_in[1];
  const int* srcIn[3] = {(const int*)d_in[2], (const int*)d_in[4], (const int*)d_in[6]};
  const int* dstIn[3] = {(const int*)d_in[3], (const int*)d_in[5], (const int*)d_in[7]};
  const float* inWc = (const float*)d_in[8];
  const float* inbc = (const float*)d_in[9];
  const float* inWq = (const float*)d_in[10];
  const float* inbq = (const float*)d_in[11];
  const float* kW = (const float*)d_in[12];
  const float* kB = (const float*)d_in[13];
  const float* qW = (const float*)d_in[14];
  const float* qB = (const float*)d_in[15];
  const float* vW = (const float*)d_in[16];
  const float* vB = (const float*)d_in[17];
  const float* aW = (const float*)d_in[18];
  const float* aB = (const float*)d_in[19];
  const float* skip = (const float*)d_in[20];
  const float* arel = (const float*)d_in[21];
  const float* mrel = (const float*)d_in[22];
  const float* prel = (const float*)d_in[23];
  const float* outW = (const float*)d_in[24];
  const float* outb = (const float*)d_in[25];

  const int sntArr[3] = {1, 0, 0};
  const int dntArr[3] = {0, 0, 1};
  const int NsArr[2] = {NC, NQ};

  char* base = (char*)d_ws;
  size_t off = 0;
  auto carve = [&](size_t bytes) -> void* {
    void* p = base + off;
    off = align256(off + bytes);
    return p;
  };
  float* x0 = (float*)carve((size_t)NC * 128 * 4);
  float* x1 = (float*)carve((size_t)NQ * 128 * 4);
  float* q0 = (float*)carve((size_t)NC * 128 * 4);
  float* q1 = (float*)carve((size_t)NQ * 128 * 4);
  float* krel = (float*)carve((size_t)NC * 128 * 4);
  float* vrel = (float*)carve((size_t)NC * 128 * 4);
  float* agg0 = (float*)carve((size_t)NC * 128 * 4);
  float* agg1 = (float*)carve((size_t)NQ * 128 * 4);
  float* logits = (float*)carve((size_t)NEDGE * 4 * 4);
  float* Wfk = (float*)carve(128 * 128 * 4);
  float* bfk = (float*)carve(128 * 4);
  float* Wfv = (float*)carve(128 * 128 * 4);
  float* bfv = (float*)carve(128 * 4);
  int* ptrs[3];
  ptrs[0] = (int*)carve((size_t)(NC + 1) * 4);
  ptrs[1] = (int*)carve((size_t)(NC + 1) * 4);
  ptrs[2] = (int*)carve((size_t)(NQ + 1) * 4);
  int* srcs[3];
  srcs[0] = (int*)carve((size_t)NEDGE * 4);
  srcs[1] = (int*)carve((size_t)NEDGE * 4);
  srcs[2] = (int*)carve((size_t)NEDGE * 4);
  int* counts = (int*)carve((size_t)NC * 4);
  int* cursor = (int*)carve((size_t)NC * 4);
  int* blksums = (int*)carve(2048 * 4);

  // ---- CSR build (indices static across layers) ----
  for (int et = 0; et < 3; ++et) {
    int nd = NsArr[dntArr[et]];
    int nb = (nd + 255) / 256;
    hipMemsetAsync(counts, 0, (size_t)nd * 4, stream);
    k_count<<<(NEDGE + 255) / 256, 256, 0, stream>>>(dstIn[et], counts, NEDGE);
    k_scan_block<<<nb, 256, 0, stream>>>(counts, ptrs[et], blksums, nd);
    k_scan_sums<<<1, 1024, 0, stream>>>(blksums, nb);
    k_scan_add<<<nb, 256, 0, stream>>>(ptrs[et], blksums, nd, NEDGE);
    k_copy<<<nb, 256, 0, stream>>>(cursor, ptrs[et], nd);
    k_scatter<<<(NEDGE + 255) / 256, 256, 0, stream>>>(srcIn[et], dstIn[et], cursor, srcs[et], NEDGE);
  }

  // ---- input projections (relu) ----
  gemm128<1, 0><<<(NC + 63) / 64, 256, 0, stream>>>(x_context, inWc, inbc, x0, nullptr, nullptr, NC, FC);
  gemm128<1, 0><<<(NQ + 63) / 64, 256, 0, stream>>>(x_question, inWq, inbq, x1, nullptr, nullptr, NQ, FQ);

  float* xs[2] = {x0, x1};
  float* qs[2] = {q0, q1};
  float* aggs[2] = {agg0, agg1};

  for (int l = 0; l < 2; ++l) {
    for (int nt = 0; nt < 2; ++nt)
      gemm128<0, 0><<<(NsArr[nt] + 63) / 64, 256, 0, stream>>>(
          xs[nt], qW + (size_t)(l * 2 + nt) * 16384, qB + (size_t)(l * 2 + nt) * 128,
          qs[nt], nullptr, nullptr, NsArr[nt], 128);
    hipMemsetAsync(agg0, 0, (size_t)NC * 128 * 4, stream);
    hipMemsetAsync(agg1, 0, (size_t)NQ * 128 * 4, stream);

    for (int et = 0; et < 3; ++et) {
      int s = sntArr[et], d = dntArr[et];
      fold_kernel<<<128, 128, 0, stream>>>(kW + (size_t)(l * 2 + s) * 16384,
                                           kB + (size_t)(l * 2 + s) * 128,
                                           arel + (size_t)(l * 3 + et) * 4096,
                                           prel + (size_t)(l * 3 + et) * 4, SCALE, Wfk, bfk);
      fold_kernel<<<128, 128, 0, stream>>>(vW + (size_t)(l * 2 + s) * 16384,
                                           vB + (size_t)(l * 2 + s) * 128,
                                           mrel + (size_t)(l * 3 + et) * 4096,
                                           nullptr, 1.0f, Wfv, bfv);
      gemm128<0, 0><<<(NsArr[s] + 63) / 64, 256, 0, stream>>>(xs[s], Wfk, bfk, krel, nullptr, nullptr, NsArr[s], 128);
      gemm128<0, 0><<<(NsArr[s] + 63) / 64, 256, 0, stream>>>(xs[s], Wfv, bfv, vrel, nullptr, nullptr, NsArr[s], 128);
      attn_kernel<<<(NsArr[d] + 3) / 4, 256, 0, stream>>>(qs[d], krel, vrel, ptrs[et], srcs[et],
                                                          aggs[d], logits, NsArr[d]);
    }
    for (int nt = 0; nt < 2; ++nt)
      gemm128<2, 1><<<(NsArr[nt] + 63) / 64, 256, 0, stream>>>(
          aggs[nt], aW + (size_t)(l * 2 + nt) * 16384, aB + (size_t)(l * 2 + nt) * 128,
          xs[nt], xs[nt], skip + l * 2 + nt, NsArr[nt], 128);
  }

  gemm_out<<<(NC + 31) / 32, 256, 0, stream>>>(x0, outW, outb, (float*)d_out, NC);
}

// Round 2
// 1498.966 us; speedup vs baseline: 1.4280x; 1.4280x over previous
//
#include <hip/hip_runtime.h>

constexpr int NC = 100000;
constexpr int NQ = 20000;
constexpr int FC = 300;
constexpr int FQ = 768;
constexpr int NEDGE = 400000;
constexpr float SCALE = 0.17677669529663687f;  // 1/sqrt(32)

typedef __attribute__((ext_vector_type(8))) short bf16x8;
typedef __attribute__((ext_vector_type(4))) float f32x4;

__device__ __forceinline__ float gelu_f(float x) {
  return 0.5f * x * (1.0f + erff(x * 0.7071067811865476f));
}
__device__ __forceinline__ unsigned short bf16_rne(float x) {
  unsigned u = __float_as_uint(x);
  unsigned r = u + 0x7fffu + ((u >> 16) & 1u);
  return (unsigned short)(r >> 16);
}
__device__ __forceinline__ float bf16_to_f(unsigned short h) {
  return __uint_as_float(((unsigned)h) << 16);
}
__device__ __forceinline__ void split2(float x, unsigned short& hi, unsigned short& lo) {
  hi = bf16_rne(x);
  lo = bf16_rne(x - bf16_to_f(hi));
}

// ---------------- CSR build ----------------
__global__ void k_count(const int* __restrict__ dst, int* __restrict__ counts, int n) {
  int i = blockIdx.x * 256 + threadIdx.x;
  if (i < n) atomicAdd(&counts[dst[i]], 1);
}

__global__ void k_scan_block(const int* __restrict__ in, int* __restrict__ out,
                             int* __restrict__ bsum, int n) {
  __shared__ int s[256];
  int tid = threadIdx.x;
  int i = blockIdx.x * 256 + tid;
  int v = (i < n) ? in[i] : 0;
  s[tid] = v;
  __syncthreads();
  for (int off = 1; off < 256; off <<= 1) {
    int t = (tid >= off) ? s[tid - off] : 0;
    __syncthreads();
    s[tid] += t;
    __syncthreads();
  }
  if (i < n) out[i] = s[tid] - v;
  if (tid == 255) bsum[blockIdx.x] = s[255];
}

__global__ void k_scan_sums(int* __restrict__ bsum, int nb) {
  __shared__ int s[1024];
  int tid = threadIdx.x;
  int v = (tid < nb) ? bsum[tid] : 0;
  s[tid] = v;
  __syncthreads();
  for (int off = 1; off < 1024; off <<= 1) {
    int t = (tid >= off) ? s[tid - off] : 0;
    __syncthreads();
    s[tid] += t;
    __syncthreads();
  }
  if (tid < nb) bsum[tid] = s[tid] - v;
}

__global__ void k_scan_add(int* __restrict__ ptr, const int* __restrict__ bsum, int n, int total) {
  int i = blockIdx.x * 256 + threadIdx.x;
  if (i < n) ptr[i] += bsum[blockIdx.x];
  if (i == 0) ptr[n] = total;
}

__global__ void k_copy(int* __restrict__ dst, const int* __restrict__ src, int n) {
  int i = blockIdx.x * 256 + threadIdx.x;
  if (i < n) dst[i] = src[i];
}

__global__ void k_scatter(const int* __restrict__ src, const int* __restrict__ dst,
                          int* __restrict__ cursor, int* __restrict__ srcs_out, int n) {
  int i = blockIdx.x * 256 + threadIdx.x;
  if (i < n) {
    int p = atomicAdd(&cursor[dst[i]], 1);
    srcs_out[p] = src[i];
  }
}

// ---------------- fold k/v weights with a_rel/m_rel, emit split+transposed B ----------------
// Bt[n][k] layout ([N x Kp] bf16 hi/lo), bias folded too.
__global__ void fold_split(const float* __restrict__ Win, const float* __restrict__ bin,
                           const float* __restrict__ rel, const float* __restrict__ prel,
                           float scale, unsigned short* __restrict__ Bth,
                           unsigned short* __restrict__ Btl, float* __restrict__ biasOut,
                           int colOff, int Kp) {
  int i = blockIdx.x;     // input dim (k) 0..127
  int col = threadIdx.x;  // output col 0..127
  int h = col >> 5, f = col & 31;
  float m = (prel ? prel[h] : 1.0f) * scale;
  float s = 0.0f;
  #pragma unroll
  for (int d = 0; d < 32; ++d)
    s += Win[i * 128 + h * 32 + d] * rel[(h * 32 + d) * 32 + f];
  s *= m;
  unsigned short hi, lo;
  split2(s, hi, lo);
  Bth[(size_t)(colOff + col) * Kp + i] = hi;
  Btl[(size_t)(colOff + col) * Kp + i] = lo;
  if (i == 0) {
    float sb = 0.0f;
    #pragma unroll
    for (int d = 0; d < 32; ++d)
      sb += bin[h * 32 + d] * rel[(h * 32 + d) * 32 + f];
    biasOut[colOff + col] = sb * m;
  }
}

// ---------------- split+transpose a plain weight W[KxN] -> Bt[N x Kp] hi/lo ----------------
__global__ void split_w(const float* __restrict__ W, const float* __restrict__ b,
                        unsigned short* __restrict__ Bth, unsigned short* __restrict__ Btl,
                        float* __restrict__ biasOut, int K, int Kp, int N) {
  int n = blockIdx.x;
  for (int k = threadIdx.x; k < Kp; k += blockDim.x) {
    float v = (k < K) ? W[(size_t)k * N + n] : 0.0f;
    unsigned short hi, lo;
    split2(v, hi, lo);
    Bth[(size_t)n * Kp + k] = hi;
    Btl[(size_t)n * Kp + k] = lo;
  }
  if (threadIdx.x == 0) biasOut[n] = b[n];
}

// ---------------- split-bf16 MFMA GEMM ----------------
// C[M x N] = epi(A[M x K] @ B[K x N] + bias), N = 128*gridDim.y
// A via 3-term split: Ah*Bh + Al*Bh + Ah*Bl (residual ~2^-18)
// MODE 0: plain  1: relu  2: skip-gate (g*o + (1-g)*xold)
// GIN: exact gelu applied to A on load (AF32 path only)
// AF32: A is f32 (split in-kernel); else A is pre-split hi/lo bf16 [M x Kpa]
// WSPLIT: write C as split hi/lo bf16 pair [M x 128]; else f32 [M x ldc]
template <int MODE, int GIN, int AF32, int WSPLIT>
__global__ __launch_bounds__(256) void gemm_mfma(
    const float* __restrict__ A32, const unsigned short* __restrict__ Ahg,
    const unsigned short* __restrict__ Alg, const unsigned short* __restrict__ Bth,
    const unsigned short* __restrict__ Btl, const float* __restrict__ bias,
    float* __restrict__ C32, unsigned short* __restrict__ Ch, unsigned short* __restrict__ Cl,
    const unsigned short* __restrict__ Xoh, const unsigned short* __restrict__ Xol,
    const float* __restrict__ skip_p, int M, int K, int Kp, int Kpa, int ldc) {
  __shared__ unsigned short Ah[128][40];
  __shared__ unsigned short Al[128][40];
  __shared__ unsigned short Bh[128][40];
  __shared__ unsigned short Bl[128][40];
  const int tid = threadIdx.x;
  const int m0 = blockIdx.x * 128;
  const int n0 = blockIdx.y * 128;
  const int lane = tid & 63;
  const int wv = tid >> 6;
  const int l15 = lane & 15;
  const int koff = (lane >> 4) * 8;
  const int sr = tid >> 1;        // staging row 0..127
  const int sc = (tid & 1) * 16;  // staging col-half (bf16 units)
  const bool rowok = (m0 + sr) < M;

  f32x4 acc[2][8];
  #pragma unroll
  for (int mi = 0; mi < 2; ++mi)
    #pragma unroll
    for (int ni = 0; ni < 8; ++ni) acc[mi][ni] = (f32x4){0.f, 0.f, 0.f, 0.f};

  for (int k0 = 0; k0 < K; k0 += 32) {
    // ---- stage A ----
    if (AF32) {
      float va[16];
      if (rowok && (k0 + 32 <= K)) {
        const float* ap = A32 + (size_t)(m0 + sr) * K + k0 + sc;
        #pragma unroll
        for (int j = 0; j < 4; ++j) {
          float4 f = *(const float4*)(ap + 4 * j);
          va[4 * j + 0] = f.x; va[4 * j + 1] = f.y; va[4 * j + 2] = f.z; va[4 * j + 3] = f.w;
        }
      } else {
        #pragma unroll
        for (int j = 0; j < 16; ++j) {
          int kc = k0 + sc + j;
          va[j] = (rowok && kc < K) ? A32[(size_t)(m0 + sr) * K + kc] : 0.0f;
        }
      }
      alignas(16) unsigned short hv[16];
      alignas(16) unsigned short lv[16];
      #pragma unroll
      for (int j = 0; j < 16; ++j) {
        float x = GIN ? gelu_f(va[j]) : va[j];
        split2(x, hv[j], lv[j]);
      }
      *(uint4*)&Ah[sr][sc] = *(const uint4*)&hv[0];
      *(uint4*)&Ah[sr][sc + 8] = *(const uint4*)&hv[8];
      *(uint4*)&Al[sr][sc] = *(const uint4*)&lv[0];
      *(uint4*)&Al[sr][sc + 8] = *(const uint4*)&lv[8];
    } else {
      uint4 h0 = {0, 0, 0, 0}, h1 = {0, 0, 0, 0}, l0 = {0, 0, 0, 0}, l1 = {0, 0, 0, 0};
      if (rowok) {
        const unsigned short* ap = Ahg + (size_t)(m0 + sr) * Kpa + k0 + sc;
        h0 = *(const uint4*)ap;
        h1 = *(const uint4*)(ap + 8);
        const unsigned short* lp = Alg + (size_t)(m0 + sr) * Kpa + k0 + sc;
        l0 = *(const uint4*)lp;
        l1 = *(const uint4*)(lp + 8);
      }
      *(uint4*)&Ah[sr][sc] = h0;
      *(uint4*)&Ah[sr][sc + 8] = h1;
      *(uint4*)&Al[sr][sc] = l0;
      *(uint4*)&Al[sr][sc + 8] = l1;
    }
    // ---- stage B (always pre-split, padded to Kp) ----
    {
      const unsigned short* bp = Bth + (size_t)(n0 + sr) * Kp + k0 + sc;
      *(uint4*)&Bh[sr][sc] = *(const uint4*)bp;
      *(uint4*)&Bh[sr][sc + 8] = *(const uint4*)(bp + 8);
      const unsigned short* lp = Btl + (size_t)(n0 + sr) * Kp + k0 + sc;
      *(uint4*)&Bl[sr][sc] = *(const uint4*)lp;
      *(uint4*)&Bl[sr][sc + 8] = *(const uint4*)(lp + 8);
    }
    __syncthreads();

    bf16x8 a_h[2], a_l[2];
    #pragma unroll
    for (int mi = 0; mi < 2; ++mi) {
      int row = wv * 32 + mi * 16 + l15;
      a_h[mi] = *(const bf16x8*)&Ah[row][koff];
      a_l[mi] = *(const bf16x8*)&Al[row][koff];
    }
    #pragma unroll
    for (int ni = 0; ni < 8; ++ni) {
      int col = ni * 16 + l15;
      bf16x8 b_h = *(const bf16x8*)&Bh[col][koff];
      bf16x8 b_l = *(const bf16x8*)&Bl[col][koff];
      #pragma unroll
      for (int mi = 0; mi < 2; ++mi) {
        acc[mi][ni] = __builtin_amdgcn_mfma_f32_16x16x32_bf16(a_h[mi], b_h, acc[mi][ni], 0, 0, 0);
        acc[mi][ni] = __builtin_amdgcn_mfma_f32_16x16x32_bf16(a_l[mi], b_h, acc[mi][ni], 0, 0, 0);
        acc[mi][ni] = __builtin_amdgcn_mfma_f32_16x16x32_bf16(a_h[mi], b_l, acc[mi][ni], 0, 0, 0);
      }
    }
    __syncthreads();
  }

  float g = 1.0f;
  if (MODE == 2) g = 1.0f / (1.0f + __expf(-skip_p[0]));

  #pragma unroll
  for (int mi = 0; mi < 2; ++mi) {
    #pragma unroll
    for (int ni = 0; ni < 8; ++ni) {
      int col = n0 + ni * 16 + l15;
      float bi = bias[col];
      int rbase = m0 + wv * 32 + mi * 16 + (lane >> 4) * 4;
      #pragma unroll
      for (int rr = 0; rr < 4; ++rr) {
        int row = rbase + rr;
        if (row >= M) continue;
        float o = acc[mi][ni][rr] + bi;
        if (MODE == 1) o = fmaxf(o, 0.0f);
        if (MODE == 2) {
          float xo = bf16_to_f(Xoh[(size_t)row * 128 + col]) + bf16_to_f(Xol[(size_t)row * 128 + col]);
          o = g * o + (1.0f - g) * xo;
        }
        if (WSPLIT) {
          unsigned short hh, ll;
          split2(o, hh, ll);
          Ch[(size_t)row * 128 + col] = hh;
          Cl[(size_t)row * 128 + col] = ll;
        } else {
          C32[(size_t)row * ldc + col] = o;
        }
      }
    }
  }
}

// ---------------- attention: one wave per dst node, online softmax, single pass ----------------
__global__ __launch_bounds__(256) void attn_kernel(
    const float* __restrict__ q,    // [Ndst x 128]
    const float* __restrict__ kv,   // [Nsrc x 256]  (k | v)
    const int* __restrict__ ptr, const int* __restrict__ srcs,
    float* __restrict__ agg, int Ndst) {
  int wave = threadIdx.x >> 6;
  int lane = threadIdx.x & 63;
  int n = blockIdx.x * 4 + wave;
  if (n >= Ndst) return;
  int start = ptr[n], end = ptr[n + 1];
  if (start == end) return;
  float2 q2 = *(const float2*)&q[(size_t)n * 128 + lane * 2];
  float mx = -3.0e38f, sum = 0.0f;
  float2 acc = make_float2(0.0f, 0.0f);
  for (int e = start; e < end; ++e) {
    int s = srcs[e];
    const float* row = &kv[(size_t)s * 256];
    float2 kr = *(const float2*)&row[lane * 2];
    float p = q2.x * kr.x + q2.y * kr.y;
    p += __shfl_xor(p, 1);
    p += __shfl_xor(p, 2);
    p += __shfl_xor(p, 4);
    p += __shfl_xor(p, 8);
    if (p > mx) {
      float sc = __expf(mx - p);
      sum *= sc; acc.x *= sc; acc.y *= sc;
      mx = p;
    }
    float w = __expf(p - mx);
    sum += w;
    float2 vr = *(const float2*)&row[128 + lane * 2];
    acc.x += w * vr.x;
    acc.y += w * vr.y;
  }
  float inv = 1.0f / (sum + 1e-16f);
  float2 a2 = *(float2*)&agg[(size_t)n * 128 + lane * 2];
  a2.x += acc.x * inv;
  a2.y += acc.y * inv;
  *(float2*)&agg[(size_t)n * 128 + lane * 2] = a2;
}

// ---------------- final projection: out[M x 8] = (xh+xl)[M x 128] @ W[128 x 8] + b
__global__ __launch_bounds__(256) void gemm_out(const unsigned short* __restrict__ Xh,
                                                const unsigned short* __restrict__ Xl,
                                                const float* __restrict__ W,
                                                const float* __restrict__ b,
                                                float* __restrict__ out, int M) {
  __shared__ float Ws[1024];
  __shared__ float As[32][129];
  int tid = threadIdx.x;
  int m0 = blockIdx.x * 32;
  *(float4*)&Ws[tid * 4] = *(const float4*)&W[tid * 4];
  {
    int r = tid >> 3;
    int c0 = (tid & 7) * 16;
    if (m0 + r < M) {
      const unsigned short* hp = Xh + (size_t)(m0 + r) * 128 + c0;
      const unsigned short* lp = Xl + (size_t)(m0 + r) * 128 + c0;
      #pragma unroll
      for (int j = 0; j < 16; ++j) As[r][c0 + j] = bf16_to_f(hp[j]) + bf16_to_f(lp[j]);
    } else {
      #pragma unroll
      for (int j = 0; j < 16; ++j) As[r][c0 + j] = 0.0f;
    }
  }
  __syncthreads();
  int r = tid >> 3, c = tid & 7;
  float sum = b[c];
  #pragma unroll 16
  for (int k = 0; k < 128; ++k) sum = fmaf(As[r][k], Ws[k * 8 + c], sum);
  if (m0 + r < M) out[(size_t)(m0 + r) * 8 + c] = sum;
}

// ---------------- host orchestration ----------------
static inline size_t align256(size_t x) { return (x + 255) & ~(size_t)255; }

extern "C" void kernel_launch(void* const* d_in, const int* in_sizes, int n_in,
                              void* d_out, int out_size, void* d_ws, size_t ws_size,
                              hipStream_t stream) {
  const float* x_context = (const float*)d_in[0];
  const float* x_question = (const float*)d_in[1];
  const int* srcIn[3] = {(const int*)d_in[2], (const int*)d_in[4], (const int*)d_in[6]};
  const int* dstIn[3] = {(const int*)d_in[3], (const int*)d_in[5], (const int*)d_in[7]};
  const float* inWc = (const float*)d_in[8];
  const float* inbc = (const float*)d_in[9];
  const float* inWq = (const float*)d_in[10];
  const float* inbq = (const float*)d_in[11];
  const float* kW = (const float*)d_in[12];
  const float* kB = (const float*)d_in[13];
  const float* qW = (const float*)d_in[14];
  const float* qB = (const float*)d_in[15];
  const float* vW = (const float*)d_in[16];
  const float* vB = (const float*)d_in[17];
  const float* aW = (const float*)d_in[18];
  const float* aB = (const float*)d_in[19];
  const float* skip = (const float*)d_in[20];
  const float* arel = (const float*)d_in[21];
  const float* mrel = (const float*)d_in[22];
  const float* prel = (const float*)d_in[23];
  const float* outW = (const float*)d_in[24];
  const float* outb = (const float*)d_in[25];

  const int sntArr[3] = {1, 0, 0};
  const int dntArr[3] = {0, 0, 1};
  const int NsArr[2] = {NC, NQ};

  char* base = (char*)d_ws;
  size_t off = 0;
  auto carve = [&](size_t bytes) -> void* {
    void* p = base + off;
    off = align256(off + bytes);
    return p;
  };
  unsigned short* x0h = (unsigned short*)carve((size_t)NC * 128 * 2);
  unsigned short* x0l = (unsigned short*)carve((size_t)NC * 128 * 2);
  unsigned short* x1h = (unsigned short*)carve((size_t)NQ * 128 * 2);
  unsigned short* x1l = (unsigned short*)carve((size_t)NQ * 128 * 2);
  float* q0 = (float*)carve((size_t)NC * 128 * 4);
  float* q1 = (float*)carve((size_t)NQ * 128 * 4);
  float* kv = (float*)carve((size_t)NC * 256 * 4);
  float* agg0 = (float*)carve((size_t)NC * 128 * 4);
  float* agg1 = (float*)carve((size_t)NQ * 128 * 4);
  unsigned short* Bth = (unsigned short*)carve((size_t)256 * 768 * 2);
  unsigned short* Btl = (unsigned short*)carve((size_t)256 * 768 * 2);
  float* biasBuf = (float*)carve(256 * 4);
  int* ptrs[3];
  ptrs[0] = (int*)carve((size_t)(NC + 1) * 4);
  ptrs[1] = (int*)carve((size_t)(NC + 1) * 4);
  ptrs[2] = (int*)carve((size_t)(NQ + 1) * 4);
  int* srcs[3];
  srcs[0] = (int*)carve((size_t)NEDGE * 4);
  srcs[1] = (int*)carve((size_t)NEDGE * 4);
  srcs[2] = (int*)carve((size_t)NEDGE * 4);
  int* counts = (int*)carve((size_t)NC * 4);
  int* cursor = (int*)carve((size_t)NC * 4);
  int* blksums = (int*)carve(2048 * 4);

  // ---- CSR build ----
  for (int et = 0; et < 3; ++et) {
    int nd = NsArr[dntArr[et]];
    int nb = (nd + 255) / 256;
    hipMemsetAsync(counts, 0, (size_t)nd * 4, stream);
    k_count<<<(NEDGE + 255) / 256, 256, 0, stream>>>(dstIn[et], counts, NEDGE);
    k_scan_block<<<nb, 256, 0, stream>>>(counts, ptrs[et], blksums, nd);
    k_scan_sums<<<1, 1024, 0, stream>>>(blksums, nb);
    k_scan_add<<<nb, 256, 0, stream>>>(ptrs[et], blksums, nd, NEDGE);
    k_copy<<<nb, 256, 0, stream>>>(cursor, ptrs[et], nd);
    k_scatter<<<(NEDGE + 255) / 256, 256, 0, stream>>>(srcIn[et], dstIn[et], cursor, srcs[et], NEDGE);
  }

  // ---- input projections: relu(x @ W + b) -> split pair ----
  split_w<<<128, 256, 0, stream>>>(inWc, inbc, Bth, Btl, biasBuf, FC, 320, 128);
  gemm_mfma<1, 0, 1, 1><<<dim3((NC + 127) / 128, 1), 256, 0, stream>>>(
      x_context, nullptr, nullptr, Bth, Btl, biasBuf, nullptr, x0h, x0l,
      nullptr, nullptr, nullptr, NC, FC, 320, 0, 128);
  split_w<<<128, 256, 0, stream>>>(inWq, inbq, Bth, Btl, biasBuf, FQ, 768, 128);
  gemm_mfma<1, 0, 1, 1><<<dim3((NQ + 127) / 128, 1), 256, 0, stream>>>(
      x_question, nullptr, nullptr, Bth, Btl, biasBuf, nullptr, x1h, x1l,
      nullptr, nullptr, nullptr, NQ, FQ, 768, 0, 128);

  unsigned short* xh[2] = {x0h, x1h};
  unsigned short* xl[2] = {x0l, x1l};
  float* qs[2] = {q0, q1};
  float* aggs[2] = {agg0, agg1};

  for (int l = 0; l < 2; ++l) {
    // q projections
    for (int nt = 0; nt < 2; ++nt) {
      split_w<<<128, 256, 0, stream>>>(qW + (size_t)(l * 2 + nt) * 16384,
                                       qB + (size_t)(l * 2 + nt) * 128, Bth, Btl, biasBuf, 128, 128, 128);
      gemm_mfma<0, 0, 0, 0><<<dim3((NsArr[nt] + 127) / 128, 1), 256, 0, stream>>>(
          nullptr, xh[nt], xl[nt], Bth, Btl, biasBuf, qs[nt], nullptr, nullptr,
          nullptr, nullptr, nullptr, NsArr[nt], 128, 128, 128, 128);
    }
    hipMemsetAsync(agg0, 0, (size_t)NC * 128 * 4, stream);
    hipMemsetAsync(agg1, 0, (size_t)NQ * 128 * 4, stream);

    for (int et = 0; et < 3; ++et) {
      int s = sntArr[et], d = dntArr[et];
      fold_split<<<128, 128, 0, stream>>>(kW + (size_t)(l * 2 + s) * 16384,
                                          kB + (size_t)(l * 2 + s) * 128,
                                          arel + (size_t)(l * 3 + et) * 4096,
                                          prel + (size_t)(l * 3 + et) * 4, SCALE,
                                          Bth, Btl, biasBuf, 0, 128);
      fold_split<<<128, 128, 0, stream>>>(vW + (size_t)(l * 2 + s) * 16384,
                                          vB + (size_t)(l * 2 + s) * 128,
                                          mrel + (size_t)(l * 3 + et) * 4096,
                                          nullptr, 1.0f, Bth, Btl, biasBuf, 128, 128);
      gemm_mfma<0, 0, 0, 0><<<dim3((NsArr[s] + 127) / 128, 2), 256, 0, stream>>>(
          nullptr, xh[s], xl[s], Bth, Btl, biasBuf, kv, nullptr, nullptr,
          nullptr, nullptr, nullptr, NsArr[s], 128, 128, 128, 256);
      attn_kernel<<<(NsArr[d] + 3) / 4, 256, 0, stream>>>(qs[d], kv, ptrs[et], srcs[et],
                                                          aggs[d], NsArr[d]);
    }
    // a-projection + gelu + skip-gate, write back into x pair
    for (int nt = 0; nt < 2; ++nt) {
      split_w<<<128, 256, 0, stream>>>(aW + (size_t)(l * 2 + nt) * 16384,
                                       aB + (size_t)(l * 2 + nt) * 128, Bth, Btl, biasBuf, 128, 128, 128);
      gemm_mfma<2, 1, 1, 1><<<dim3((NsArr[nt] + 127) / 128, 1), 256, 0, stream>>>(
          aggs[nt], nullptr, nullptr, Bth, Btl, biasBuf, nullptr, xh[nt], xl[nt],
          xh[nt], xl[nt], skip + l * 2 + nt, NsArr[nt], 128, 128, 0, 128);
    }
  }

  gemm_out<<<(NC + 31) / 32, 256, 0, stream>>>(x0h, x0l, outW, outb, (float*)d_out, NC);
}

// Round 3
// 1217.042 us; speedup vs baseline: 1.7587x; 1.2316x over previous
//
#include <hip/hip_runtime.h>

constexpr int NC = 100000;
constexpr int NQ = 20000;
constexpr int FC = 300;
constexpr int FQ = 768;
constexpr int NEDGE = 400000;
constexpr float SCALE = 0.17677669529663687f;  // 1/sqrt(32)

typedef __attribute__((ext_vector_type(8))) short bf16x8;
typedef __attribute__((ext_vector_type(4))) float f32x4;

struct CDst {
  float* p[3];
  int ld[3];
  int cb[3];
};

__device__ __forceinline__ float gelu_f(float x) {
  return 0.5f * x * (1.0f + erff(x * 0.7071067811865476f));
}
__device__ __forceinline__ unsigned short bf16_rne(float x) {
  unsigned u = __float_as_uint(x);
  unsigned r = u + 0x7fffu + ((u >> 16) & 1u);
  return (unsigned short)(r >> 16);
}
__device__ __forceinline__ float bf16_to_f(unsigned short h) {
  return __uint_as_float(((unsigned)h) << 16);
}
__device__ __forceinline__ void split2(float x, unsigned short& hi, unsigned short& lo) {
  hi = bf16_rne(x);
  lo = bf16_rne(x - bf16_to_f(hi));
}

// ---------------- CSR build ----------------
__global__ void k_count(const int* __restrict__ dst, int* __restrict__ counts, int n) {
  int i = blockIdx.x * 256 + threadIdx.x;
  if (i < n) atomicAdd(&counts[dst[i]], 1);
}

__global__ void k_scan_block(const int* __restrict__ in, int* __restrict__ out,
                             int* __restrict__ bsum, int n) {
  __shared__ int s[256];
  int tid = threadIdx.x;
  int i = blockIdx.x * 256 + tid;
  int v = (i < n) ? in[i] : 0;
  s[tid] = v;
  __syncthreads();
  for (int off = 1; off < 256; off <<= 1) {
    int t = (tid >= off) ? s[tid - off] : 0;
    __syncthreads();
    s[tid] += t;
    __syncthreads();
  }
  if (i < n) out[i] = s[tid] - v;
  if (tid == 255) bsum[blockIdx.x] = s[255];
}

__global__ void k_scan_sums(int* __restrict__ bsum, int nb) {
  __shared__ int s[1024];
  int tid = threadIdx.x;
  int v = (tid < nb) ? bsum[tid] : 0;
  s[tid] = v;
  __syncthreads();
  for (int off = 1; off < 1024; off <<= 1) {
    int t = (tid >= off) ? s[tid - off] : 0;
    __syncthreads();
    s[tid] += t;
    __syncthreads();
  }
  if (tid < nb) bsum[tid] = s[tid] - v;
}

__global__ void k_scan_add(int* __restrict__ ptr, const int* __restrict__ bsum, int n, int total) {
  int i = blockIdx.x * 256 + threadIdx.x;
  if (i < n) ptr[i] += bsum[blockIdx.x];
  if (i == 0) ptr[n] = total;
}

__global__ void k_copy(int* __restrict__ dst, const int* __restrict__ src, int n) {
  int i = blockIdx.x * 256 + threadIdx.x;
  if (i < n) dst[i] = src[i];
}

__global__ void k_scatter(const int* __restrict__ src, const int* __restrict__ dst,
                          int* __restrict__ cursor, int* __restrict__ srcs_out, int n) {
  int i = blockIdx.x * 256 + threadIdx.x;
  if (i < n) {
    int p = atomicAdd(&cursor[dst[i]], 1);
    srcs_out[p] = src[i];
  }
}

// ---------------- fold k/v weights with rel, emit split+transposed B at colOff ----------------
__global__ void fold_split(const float* __restrict__ Win, const float* __restrict__ bin,
                           const float* __restrict__ rel, const float* __restrict__ prel,
                           float scale, unsigned short* __restrict__ Bth,
                           unsigned short* __restrict__ Btl, float* __restrict__ biasOut,
                           int colOff, int Kp) {
  int i = blockIdx.x;     // input dim (k) 0..127
  int col = threadIdx.x;  // output col 0..127
  int h = col >> 5, f = col & 31;
  float m = (prel ? prel[h] : 1.0f) * scale;
  float s = 0.0f;
  #pragma unroll
  for (int d = 0; d < 32; ++d)
    s += Win[i * 128 + h * 32 + d] * rel[(h * 32 + d) * 32 + f];
  s *= m;
  unsigned short hi, lo;
  split2(s, hi, lo);
  Bth[(size_t)(colOff + col) * Kp + i] = hi;
  Btl[(size_t)(colOff + col) * Kp + i] = lo;
  if (i == 0) {
    float sb = 0.0f;
    #pragma unroll
    for (int d = 0; d < 32; ++d)
      sb += bin[h * 32 + d] * rel[(h * 32 + d) * 32 + f];
    biasOut[colOff + col] = sb * m;
  }
}

// ---------------- split+transpose plain weight W[KxN] -> Bt rows [colOff..colOff+N) ----------------
__global__ void split_w(const float* __restrict__ W, const float* __restrict__ b,
                        unsigned short* __restrict__ Bth, unsigned short* __restrict__ Btl,
                        float* __restrict__ biasOut, int K, int Kp, int N, int colOff) {
  int n = blockIdx.x;
  for (int k = threadIdx.x; k < Kp; k += blockDim.x) {
    float v = (k < K) ? W[(size_t)k * N + n] : 0.0f;
    unsigned short hi, lo;
    split2(v, hi, lo);
    Bth[(size_t)(colOff + n) * Kp + k] = hi;
    Btl[(size_t)(colOff + n) * Kp + k] = lo;
  }
  if (threadIdx.x == 0) biasOut[colOff + n] = b[n];
}

// ---------------- split-bf16 MFMA GEMM, slab-routed C ----------------
template <int MODE, int GIN, int AF32, int WSPLIT>
__global__ __launch_bounds__(256) void gemm_mfma(
    const float* __restrict__ A32, const unsigned short* __restrict__ Ahg,
    const unsigned short* __restrict__ Alg, const unsigned short* __restrict__ Bth,
    const unsigned short* __restrict__ Btl, const float* __restrict__ bias,
    CDst cdst, unsigned short* __restrict__ Ch, unsigned short* __restrict__ Cl,
    const unsigned short* __restrict__ Xoh, const unsigned short* __restrict__ Xol,
    const float* __restrict__ skip_p, int M, int K, int Kp, int Kpa) {
  __shared__ unsigned short Ah[128][40];
  __shared__ unsigned short Al[128][40];
  __shared__ unsigned short Bh[128][40];
  __shared__ unsigned short Bl[128][40];
  const int tid = threadIdx.x;
  const int m0 = blockIdx.x * 128;
  const int n0 = blockIdx.y * 128;
  const int lane = tid & 63;
  const int wv = tid >> 6;
  const int l15 = lane & 15;
  const int koff = (lane >> 4) * 8;
  const int sr = tid >> 1;
  const int sc = (tid & 1) * 16;
  const bool rowok = (m0 + sr) < M;

  f32x4 acc[2][8];
  #pragma unroll
  for (int mi = 0; mi < 2; ++mi)
    #pragma unroll
    for (int ni = 0; ni < 8; ++ni) acc[mi][ni] = (f32x4){0.f, 0.f, 0.f, 0.f};

  for (int k0 = 0; k0 < K; k0 += 32) {
    if (AF32) {
      float va[16];
      if (rowok && (k0 + 32 <= K)) {
        const float* ap = A32 + (size_t)(m0 + sr) * K + k0 + sc;
        #pragma unroll
        for (int j = 0; j < 4; ++j) {
          float4 f = *(const float4*)(ap + 4 * j);
          va[4 * j + 0] = f.x; va[4 * j + 1] = f.y; va[4 * j + 2] = f.z; va[4 * j + 3] = f.w;
        }
      } else {
        #pragma unroll
        for (int j = 0; j < 16; ++j) {
          int kc = k0 + sc + j;
          va[j] = (rowok && kc < K) ? A32[(size_t)(m0 + sr) * K + kc] : 0.0f;
        }
      }
      alignas(16) unsigned short hv[16];
      alignas(16) unsigned short lv[16];
      #pragma unroll
      for (int j = 0; j < 16; ++j) {
        float x = GIN ? gelu_f(va[j]) : va[j];
        split2(x, hv[j], lv[j]);
      }
      *(uint4*)&Ah[sr][sc] = *(const uint4*)&hv[0];
      *(uint4*)&Ah[sr][sc + 8] = *(const uint4*)&hv[8];
      *(uint4*)&Al[sr][sc] = *(const uint4*)&lv[0];
      *(uint4*)&Al[sr][sc + 8] = *(const uint4*)&lv[8];
    } else {
      uint4 h0 = {0, 0, 0, 0}, h1 = {0, 0, 0, 0}, l0 = {0, 0, 0, 0}, l1 = {0, 0, 0, 0};
      if (rowok) {
        const unsigned short* ap = Ahg + (size_t)(m0 + sr) * Kpa + k0 + sc;
        h0 = *(const uint4*)ap;
        h1 = *(const uint4*)(ap + 8);
        const unsigned short* lp = Alg + (size_t)(m0 + sr) * Kpa + k0 + sc;
        l0 = *(const uint4*)lp;
        l1 = *(const uint4*)(lp + 8);
      }
      *(uint4*)&Ah[sr][sc] = h0;
      *(uint4*)&Ah[sr][sc + 8] = h1;
      *(uint4*)&Al[sr][sc] = l0;
      *(uint4*)&Al[sr][sc + 8] = l1;
    }
    {
      const unsigned short* bp = Bth + (size_t)(n0 + sr) * Kp + k0 + sc;
      *(uint4*)&Bh[sr][sc] = *(const uint4*)bp;
      *(uint4*)&Bh[sr][sc + 8] = *(const uint4*)(bp + 8);
      const unsigned short* lp = Btl + (size_t)(n0 + sr) * Kp + k0 + sc;
      *(uint4*)&Bl[sr][sc] = *(const uint4*)lp;
      *(uint4*)&Bl[sr][sc + 8] = *(const uint4*)(lp + 8);
    }
    __syncthreads();

    bf16x8 a_h[2], a_l[2];
    #pragma unroll
    for (int mi = 0; mi < 2; ++mi) {
      int row = wv * 32 + mi * 16 + l15;
      a_h[mi] = *(const bf16x8*)&Ah[row][koff];
      a_l[mi] = *(const bf16x8*)&Al[row][koff];
    }
    #pragma unroll
    for (int ni = 0; ni < 8; ++ni) {
      int col = ni * 16 + l15;
      bf16x8 b_h = *(const bf16x8*)&Bh[col][koff];
      bf16x8 b_l = *(const bf16x8*)&Bl[col][koff];
      #pragma unroll
      for (int mi = 0; mi < 2; ++mi) {
        acc[mi][ni] = __builtin_amdgcn_mfma_f32_16x16x32_bf16(a_h[mi], b_h, acc[mi][ni], 0, 0, 0);
        acc[mi][ni] = __builtin_amdgcn_mfma_f32_16x16x32_bf16(a_l[mi], b_h, acc[mi][ni], 0, 0, 0);
        acc[mi][ni] = __builtin_amdgcn_mfma_f32_16x16x32_bf16(a_h[mi], b_l, acc[mi][ni], 0, 0, 0);
      }
    }
    __syncthreads();
  }

  float g = 1.0f;
  if (MODE == 2) g = 1.0f / (1.0f + __expf(-skip_p[0]));

  float* Cp = nullptr;
  int ldcc = 0, cb = 0;
  if (!WSPLIT) {
    Cp = cdst.p[blockIdx.y];
    ldcc = cdst.ld[blockIdx.y];
    cb = cdst.cb[blockIdx.y];
  }

  #pragma unroll
  for (int mi = 0; mi < 2; ++mi) {
    #pragma unroll
    for (int ni = 0; ni < 8; ++ni) {
      int colL = ni * 16 + l15;
      float bi = bias[n0 + colL];
      int rbase = m0 + wv * 32 + mi * 16 + (lane >> 4) * 4;
      #pragma unroll
      for (int rr = 0; rr < 4; ++rr) {
        int row = rbase + rr;
        if (row >= M) continue;
        float o = acc[mi][ni][rr] + bi;
        if (MODE == 1) o = fmaxf(o, 0.0f);
        if (MODE == 2) {
          float xo = bf16_to_f(Xoh[(size_t)row * 128 + colL]) + bf16_to_f(Xol[(size_t)row * 128 + colL]);
          o = g * o + (1.0f - g) * xo;
        }
        if (WSPLIT) {
          unsigned short hh, ll;
          split2(o, hh, ll);
          Ch[(size_t)row * 128 + colL] = hh;
          Cl[(size_t)row * 128 + colL] = ll;
        } else {
          Cp[(size_t)row * ldcc + cb + colL] = o;
        }
      }
    }
  }
}

// ---------------- fused attention: one wave per dst node, NET edge types, writes agg with '=' ----
// lanes 0-31: k-side (+q); lanes 32-63: v-side. Each lane loads kv[s][4*lane .. +3].
template <int NET>
__global__ __launch_bounds__(256) void attn_fused(
    const float* __restrict__ q,
    const float* __restrict__ kv0, const float* __restrict__ kv1,
    const int* __restrict__ ptr0, const int* __restrict__ srcs0,
    const int* __restrict__ ptr1, const int* __restrict__ srcs1,
    float* __restrict__ agg, int Ndst) {
  int wave = threadIdx.x >> 6;
  int lane = threadIdx.x & 63;
  int n = blockIdx.x * 4 + wave;
  if (n >= Ndst) return;
  float4 q4 = make_float4(0.f, 0.f, 0.f, 0.f);
  if (lane < 32) q4 = *(const float4*)&q[(size_t)n * 128 + lane * 4];
  float4 total = make_float4(0.f, 0.f, 0.f, 0.f);

  #pragma unroll
  for (int et = 0; et < NET; ++et) {
    const float* kv = (et == 0) ? kv0 : kv1;
    const int* ptr = (et == 0) ? ptr0 : ptr1;
    const int* srcs = (et == 0) ? srcs0 : srcs1;
    int start = ptr[n], end = ptr[n + 1];
    float mx = -3.0e38f, sum = 0.0f;
    float4 acc = make_float4(0.f, 0.f, 0.f, 0.f);
    for (int e = start; e < end; e += 4) {
      int nb = end - e;
      nb = nb > 4 ? 4 : nb;
      int sA[4];
      #pragma unroll
      for (int j = 0; j < 4; ++j) {
        int ee = e + j;
        ee = (ee < end - 1) ? ee : (end - 1);
        sA[j] = srcs[ee];
      }
      float4 r[4];
      #pragma unroll
      for (int j = 0; j < 4; ++j)
        r[j] = *(const float4*)&kv[(size_t)sA[j] * 256 + lane * 4];
      #pragma unroll
      for (int j = 0; j < 4; ++j) {
        if (j < nb) {  // wave-uniform branch
          float p = q4.x * r[j].x + q4.y * r[j].y + q4.z * r[j].z + q4.w * r[j].w;
          p += __shfl_xor(p, 1);
          p += __shfl_xor(p, 2);
          p += __shfl_xor(p, 4);
          float mxn = fmaxf(mx, p);
          float scale = __expf(mx - mxn);
          float w = __expf(p - mxn);
          sum = sum * scale + w;
          mx = mxn;
          float scB = __shfl(scale, lane & 31);
          float wB = __shfl(w, lane & 31);
          acc.x = acc.x * scB + wB * r[j].x;
          acc.y = acc.y * scB + wB * r[j].y;
          acc.z = acc.z * scB + wB * r[j].z;
          acc.w = acc.w * scB + wB * r[j].w;
        }
      }
    }
    float invB = __shfl(1.0f / (sum + 1e-16f), lane & 31);
    total.x += acc.x * invB;
    total.y += acc.y * invB;
    total.z += acc.z * invB;
    total.w += acc.w * invB;
  }
  if (lane >= 32)
    *(float4*)&agg[(size_t)n * 128 + (lane - 32) * 4] = total;
}

// ---------------- final projection ----------------
__global__ __launch_bounds__(256) void gemm_out(const unsigned short* __restrict__ Xh,
                                                const unsigned short* __restrict__ Xl,
                                                const float* __restrict__ W,
                                                const float* __restrict__ b,
                                                float* __restrict__ out, int M) {
  __shared__ float Ws[1024];
  __shared__ float As[32][129];
  int tid = threadIdx.x;
  int m0 = blockIdx.x * 32;
  *(float4*)&Ws[tid * 4] = *(const float4*)&W[tid * 4];
  {
    int r = tid >> 3;
    int c0 = (tid & 7) * 16;
    if (m0 + r < M) {
      const unsigned short* hp = Xh + (size_t)(m0 + r) * 128 + c0;
      const unsigned short* lp = Xl + (size_t)(m0 + r) * 128 + c0;
      #pragma unroll
      for (int j = 0; j < 16; ++j) As[r][c0 + j] = bf16_to_f(hp[j]) + bf16_to_f(lp[j]);
    } else {
      #pragma unroll
      for (int j = 0; j < 16; ++j) As[r][c0 + j] = 0.0f;
    }
  }
  __syncthreads();
  int r = tid >> 3, c = tid & 7;
  float sum = b[c];
  #pragma unroll 16
  for (int k = 0; k < 128; ++k) sum = fmaf(As[r][k], Ws[k * 8 + c], sum);
  if (m0 + r < M) out[(size_t)(m0 + r) * 8 + c] = sum;
}

// ---------------- host orchestration ----------------
static inline size_t align256(size_t x) { return (x + 255) & ~(size_t)255; }

extern "C" void kernel_launch(void* const* d_in, const int* in_sizes, int n_in,
                              void* d_out, int out_size, void* d_ws, size_t ws_size,
                              hipStream_t stream) {
  const float* x_context = (const float*)d_in[0];
  const float* x_question = (const float*)d_in[1];
  const int* srcIn[3] = {(const int*)d_in[2], (const int*)d_in[4], (const int*)d_in[6]};
  const int* dstIn[3] = {(const int*)d_in[3], (const int*)d_in[5], (const int*)d_in[7]};
  const float* inWc = (const float*)d_in[8];
  const float* inbc = (const float*)d_in[9];
  const float* inWq = (const float*)d_in[10];
  const float* inbq = (const float*)d_in[11];
  const float* kW = (const float*)d_in[12];
  const float* kB = (const float*)d_in[13];
  const float* qW = (const float*)d_in[14];
  const float* qB = (const float*)d_in[15];
  const float* vW = (const float*)d_in[16];
  const float* vB = (const float*)d_in[17];
  const float* aW = (const float*)d_in[18];
  const float* aB = (const float*)d_in[19];
  const float* skip = (const float*)d_in[20];
  const float* arel = (const float*)d_in[21];
  const float* mrel = (const float*)d_in[22];
  const float* prel = (const float*)d_in[23];
  const float* outW = (const float*)d_in[24];
  const float* outb = (const float*)d_in[25];

  const int dntArr[3] = {0, 0, 1};
  const int NsArr[2] = {NC, NQ};

  char* base = (char*)d_ws;
  size_t off = 0;
  auto carve = [&](size_t bytes) -> void* {
    void* p = base + off;
    off = align256(off + bytes);
    return p;
  };
  unsigned short* x0h = (unsigned short*)carve((size_t)NC * 128 * 2);
  unsigned short* x0l = (unsigned short*)carve((size_t)NC * 128 * 2);
  unsigned short* x1h = (unsigned short*)carve((size_t)NQ * 128 * 2);
  unsigned short* x1l = (unsigned short*)carve((size_t)NQ * 128 * 2);
  float* q0 = (float*)carve((size_t)NC * 128 * 4);
  float* q1 = (float*)carve((size_t)NQ * 128 * 4);
  float* kvA = (float*)carve((size_t)NQ * 256 * 4);   // et0: question-src k|v
  float* kvB = (float*)carve((size_t)NC * 256 * 4);   // et1 (then reused for et2): context-src k|v
  float* agg0 = (float*)carve((size_t)NC * 128 * 4);
  float* agg1 = (float*)carve((size_t)NQ * 128 * 4);
  unsigned short* Bth = (unsigned short*)carve((size_t)384 * 128 * 2);
  unsigned short* Btl = (unsigned short*)carve((size_t)384 * 128 * 2);
  unsigned short* BthI = (unsigned short*)carve((size_t)128 * 768 * 2);
  unsigned short* BtlI = (unsigned short*)carve((size_t)128 * 768 * 2);
  float* biasBuf = (float*)carve(1024 * 4);
  int* ptrs[3];
  ptrs[0] = (int*)carve((size_t)(NC + 1) * 4);
  ptrs[1] = (int*)carve((size_t)(NC + 1) * 4);
  ptrs[2] = (int*)carve((size_t)(NQ + 1) * 4);
  int* srcs[3];
  srcs[0] = (int*)carve((size_t)NEDGE * 4);
  srcs[1] = (int*)carve((size_t)NEDGE * 4);
  srcs[2] = (int*)carve((size_t)NEDGE * 4);
  int* counts = (int*)carve((size_t)NC * 4);
  int* cursor = (int*)carve((size_t)NC * 4);
  int* blksums = (int*)carve(2048 * 4);

  CDst dummy = {};

  // ---- CSR build ----
  for (int et = 0; et < 3; ++et) {
    int nd = NsArr[dntArr[et]];
    int nb = (nd + 255) / 256;
    hipMemsetAsync(counts, 0, (size_t)nd * 4, stream);
    k_count<<<(NEDGE + 255) / 256, 256, 0, stream>>>(dstIn[et], counts, NEDGE);
    k_scan_block<<<nb, 256, 0, stream>>>(counts, ptrs[et], blksums, nd);
    k_scan_sums<<<1, 1024, 0, stream>>>(blksums, nb);
    k_scan_add<<<nb, 256, 0, stream>>>(ptrs[et], blksums, nd, NEDGE);
    k_copy<<<nb, 256, 0, stream>>>(cursor, ptrs[et], nd);
    k_scatter<<<(NEDGE + 255) / 256, 256, 0, stream>>>(srcIn[et], dstIn[et], cursor, srcs[et], NEDGE);
  }

  // ---- input projections ----
  split_w<<<128, 256, 0, stream>>>(inWc, inbc, BthI, BtlI, biasBuf, FC, 320, 128, 0);
  gemm_mfma<1, 0, 1, 1><<<dim3((NC + 127) / 128, 1), 256, 0, stream>>>(
      x_context, nullptr, nullptr, BthI, BtlI, biasBuf, dummy, x0h, x0l,
      nullptr, nullptr, nullptr, NC, FC, 320, 0);
  split_w<<<128, 256, 0, stream>>>(inWq, inbq, BthI, BtlI, biasBuf, FQ, 768, 128, 0);
  gemm_mfma<1, 0, 1, 1><<<dim3((NQ + 127) / 128, 1), 256, 0, stream>>>(
      x_question, nullptr, nullptr, BthI, BtlI, biasBuf, dummy, x1h, x1l,
      nullptr, nullptr, nullptr, NQ, FQ, 768, 0);

  unsigned short* xh[2] = {x0h, x1h};
  unsigned short* xl[2] = {x0l, x1l};

  for (int l = 0; l < 2; ++l) {
    size_t lw = (size_t)l * 2 * 16384;   // weight block for (l, nt=0)
    size_t lb = (size_t)l * 2 * 128;
    size_t le = (size_t)l * 3 * 4096;    // rel block for (l, et=0)
    size_t lp = (size_t)l * 3 * 4;

    // GEMM1: x0 @ [qW(l,0) | foldK(et1,src0) | foldV(et1,src0)]  -> q0, kvB
    split_w<<<128, 256, 0, stream>>>(qW + lw, qB + lb, Bth, Btl, biasBuf, 128, 128, 128, 0);
    fold_split<<<128, 128, 0, stream>>>(kW + lw, kB + lb, arel + le + 4096, prel + lp + 4,
                                        SCALE, Bth, Btl, biasBuf, 128, 128);
    fold_split<<<128, 128, 0, stream>>>(vW + lw, vB + lb, mrel + le + 4096, nullptr,
                                        1.0f, Bth, Btl, biasBuf, 256, 128);
    {
      CDst cd = {{q0, kvB, kvB}, {128, 256, 256}, {0, 0, 128}};
      gemm_mfma<0, 0, 0, 0><<<dim3((NC + 127) / 128, 3), 256, 0, stream>>>(
          nullptr, x0h, x0l, Bth, Btl, biasBuf, cd, nullptr, nullptr,
          nullptr, nullptr, nullptr, NC, 128, 128, 128);
    }
    // GEMM2: x1 @ [qW(l,1) | foldK(et0,src1) | foldV(et0,src1)] -> q1, kvA
    split_w<<<128, 256, 0, stream>>>(qW + lw + 16384, qB + lb + 128, Bth, Btl, biasBuf, 128, 128, 128, 0);
    fold_split<<<128, 128, 0, stream>>>(kW + lw + 16384, kB + lb + 128, arel + le, prel + lp,
                                        SCALE, Bth, Btl, biasBuf, 128, 128);
    fold_split<<<128, 128, 0, stream>>>(vW + lw + 16384, vB + lb + 128, mrel + le, nullptr,
                                        1.0f, Bth, Btl, biasBuf, 256, 128);
    {
      CDst cd = {{q1, kvA, kvA}, {128, 256, 256}, {0, 0, 128}};
      gemm_mfma<0, 0, 0, 0><<<dim3((NQ + 127) / 128, 3), 256, 0, stream>>>(
          nullptr, x1h, x1l, Bth, Btl, biasBuf, cd, nullptr, nullptr,
          nullptr, nullptr, nullptr, NQ, 128, 128, 128);
    }
    // attention to context dst: et0 (kvA) + et1 (kvB)
    attn_fused<2><<<(NC + 3) / 4, 256, 0, stream>>>(q0, kvA, kvB, ptrs[0], srcs[0],
                                                    ptrs[1], srcs[1], agg0, NC);
    // GEMM3: x0 @ [foldK(et2,src0) | foldV(et2,src0)] -> kvB (reuse)
    fold_split<<<128, 128, 0, stream>>>(kW + lw, kB + lb, arel + le + 8192, prel + lp + 8,
                                        SCALE, Bth, Btl, biasBuf, 0, 128);
    fold_split<<<128, 128, 0, stream>>>(vW + lw, vB + lb, mrel + le + 8192, nullptr,
                                        1.0f, Bth, Btl, biasBuf, 128, 128);
    {
      CDst cd = {{kvB, kvB, nullptr}, {256, 256, 0}, {0, 128, 0}};
      gemm_mfma<0, 0, 0, 0><<<dim3((NC + 127) / 128, 2), 256, 0, stream>>>(
          nullptr, x0h, x0l, Bth, Btl, biasBuf, cd, nullptr, nullptr,
          nullptr, nullptr, nullptr, NC, 128, 128, 128);
    }
    // attention to question dst: et2 (kvB)
    attn_fused<1><<<(NQ + 3) / 4, 256, 0, stream>>>(q1, kvB, nullptr, ptrs[2], srcs[2],
                                                    nullptr, nullptr, agg1, NQ);

    // a-projections with gelu + skip-gate
    float* aggs[2] = {agg0, agg1};
    for (int nt = 0; nt < 2; ++nt) {
      split_w<<<128, 256, 0, stream>>>(aW + lw + (size_t)nt * 16384, aB + lb + (size_t)nt * 128,
                                       Bth, Btl, biasBuf, 128, 128, 128, 0);
      gemm_mfma<2, 1, 1, 1><<<dim3((NsArr[nt] + 127) / 128, 1), 256, 0, stream>>>(
          aggs[nt], nullptr, nullptr, Bth, Btl, biasBuf, dummy, xh[nt], xl[nt],
          xh[nt], xl[nt], skip + l * 2 + nt, NsArr[nt], 128, 128, 0);
    }
  }

  gemm_out<<<(NC + 31) / 32, 256, 0, stream>>>(x0h, x0l, outW, outb, (float*)d_out, NC);
}